// Round 5
// baseline (204.059 us; speedup 1.0000x reference)
//
#include <hip/hip_runtime.h>

// Shapes (fixed): B=4, T=2048, C=768, H=8, hs=96
constexpr int Bn = 4;
constexpr int Tn = 2048;
constexpr int Cn = 768;
constexpr int Hn = 8;
constexpr int HSn = 96;
constexpr int MR = Bn * Tn;       // 8192
constexpr int NQKV = 3 * Cn;      // 2304

typedef __attribute__((ext_vector_type(8))) short bf16x8;
typedef __attribute__((ext_vector_type(4))) float f32x4;

__device__ inline short f2bf(float f) {
  union { float f; unsigned u; } cv; cv.f = f;
  unsigned u = cv.u;
  u += 0x7fffu + ((u >> 16) & 1u);   // RNE; inputs are finite
  return (short)(u >> 16);
}

__device__ inline void gload_lds16(const short* g, short* l) {
  __builtin_amdgcn_global_load_lds(
      (const __attribute__((address_space(1))) unsigned*)g,
      (__attribute__((address_space(3))) unsigned*)l, 16, 0, 0);
}

// ---------------------------------------------------------------------------
// fp32 -> bf16 elementwise (8 elems/thread, exact grid)
// ---------------------------------------------------------------------------
__global__ __launch_bounds__(256) void cvt_bf16(const float* __restrict__ in,
                                                short* __restrict__ out) {
  const size_t i = ((size_t)blockIdx.x * 256 + threadIdx.x) * 8;
  float4 a = *(const float4*)(in + i);
  float4 b = *(const float4*)(in + i + 4);
  bf16x8 o;
  o[0] = f2bf(a.x); o[1] = f2bf(a.y); o[2] = f2bf(a.z); o[3] = f2bf(a.w);
  o[4] = f2bf(b.x); o[5] = f2bf(b.y); o[6] = f2bf(b.z); o[7] = f2bf(b.w);
  *(bf16x8*)(out + i) = o;
}

// ---------------------------------------------------------------------------
// W [K][N] fp32 -> Wt [N][K] bf16 (32x32 LDS tile transpose)
// ---------------------------------------------------------------------------
__global__ __launch_bounds__(256) void transpose_bf16(
    const float* __restrict__ W, short* __restrict__ Wt, int K, int N) {
  __shared__ float t[32][33];
  const int n0 = blockIdx.x * 32, k0 = blockIdx.y * 32;
  const int tx = threadIdx.x & 31, ty = threadIdx.x >> 5;
  #pragma unroll
  for (int i = 0; i < 32; i += 8)
    t[ty + i][tx] = W[(size_t)(k0 + ty + i) * N + n0 + tx];
  __syncthreads();
  #pragma unroll
  for (int i = 0; i < 32; i += 8)
    Wt[(size_t)(n0 + ty + i) * K + k0 + tx] = f2bf(t[tx][ty + i]);
}

// ---------------------------------------------------------------------------
// bf16 MFMA GEMM (m97 structure): C[M,N] = A[M,K] @ Bt[N,K]^T + bias[N]
// 1D grid with bijective XCD-chunked remap (gridDim.x % 8 == 0).
// ---------------------------------------------------------------------------
template <bool BF16OUT>
__global__ __launch_bounds__(256) void gemm_mfma(
    const short* __restrict__ A, const short* __restrict__ Bt,
    const float* __restrict__ bias, float* __restrict__ Cf,
    short* __restrict__ Cb, int M, int N, int K, int nxTiles,
    int scale_cols, float scale) {
  __shared__ short As[128 * 32];
  __shared__ short Bs[128 * 32];

  const int cpx = gridDim.x >> 3;
  const int lin = blockIdx.x;
  const int remap = (lin & 7) * cpx + (lin >> 3);   // XCD-chunked, bijective
  const int bxt = remap % nxTiles, byt = remap / nxTiles;

  const int tid  = threadIdx.x;
  const int wave = tid >> 6, lane = tid & 63;
  const int bm = byt * 128, bn = bxt * 128;
  const int wr = wave >> 1, wc = wave & 1;
  const int g = lane >> 4, c = lane & 15;

  f32x4 acc[4][4] = {};

  for (int k0 = 0; k0 < K; k0 += 32) {
    __syncthreads();
    #pragma unroll
    for (int cc = 0; cc < 2; ++cc) {
      const int chunkbase = (wave * 2 + cc) * 64;
      const int chunk = chunkbase + lane;
      const int row = chunk >> 2, col16 = chunk & 3;
      gload_lds16(A + (size_t)(bm + row) * K + k0 + col16 * 8,
                  &As[chunkbase * 8]);
      gload_lds16(Bt + (size_t)(bn + row) * K + k0 + col16 * 8,
                  &Bs[chunkbase * 8]);
    }
    __syncthreads();

    bf16x8 af[4], bfr[4];
    #pragma unroll
    for (int m = 0; m < 4; ++m)
      af[m] = *(const bf16x8*)&As[(wr * 64 + m * 16 + c) * 32 + g * 8];
    #pragma unroll
    for (int n = 0; n < 4; ++n)
      bfr[n] = *(const bf16x8*)&Bs[(wc * 64 + n * 16 + c) * 32 + g * 8];
    #pragma unroll
    for (int m = 0; m < 4; ++m)
      #pragma unroll
      for (int n = 0; n < 4; ++n)
        acc[m][n] = __builtin_amdgcn_mfma_f32_16x16x32_bf16(af[m], bfr[n], acc[m][n], 0, 0, 0);
  }

  #pragma unroll
  for (int n = 0; n < 4; ++n) {
    const int col = bn + wc * 64 + n * 16 + c;
    const float bs = bias[col];
    const float sc = (BF16OUT && col < scale_cols) ? scale : 1.f;
    #pragma unroll
    for (int m = 0; m < 4; ++m) {
      #pragma unroll
      for (int r = 0; r < 4; ++r) {
        const int row = bm + wr * 64 + m * 16 + g * 4 + r;
        const float v = acc[m][n][r] + bs;
        if (BF16OUT) Cb[(size_t)row * N + col] = f2bf(v * sc);
        else         Cf[(size_t)row * N + col] = v;
      }
    }
  }
}

// ---------------------------------------------------------------------------
// Causal flash attention, bf16 MFMA, fp32 accumulate.
// 4 waves/block, 16 q-rows/wave, q-tile pair {bx, 31-bx} per block.
// XCD remap keeps each (b,h)'s K/V on one XCD's L2.
// LDS 53,248 B -> 3 blocks/CU. K double-buffered (256 B swizzled rows),
// V single-buffered + end barrier, P per-wave. All LDS accesses use the
// uniform swizzle  phys_short = logical_short ^ ((row&7)*8)  -> conflict-free.
// ---------------------------------------------------------------------------
__global__ __launch_bounds__(256) void attn_mfma(
    const short* __restrict__ qkv, short* __restrict__ y) {
  __shared__ short KsBuf[2 * 64 * 128];   // 32,768 B  (rows padded to 256 B)
  __shared__ short VtBuf[96 * 64];        // 12,288 B  (transposed V)
  __shared__ short PlBuf[4 * 16 * 64];    //  8,192 B  (per-wave P)

  const int bid = blockIdx.x;
  const int xcd = bid & 7, jj = bid >> 3;
  const int p = xcd + 8 * (jj >> 4);     // (b,h) pair 0..31
  const int bx = jj & 15;
  const int b = p >> 3, h = p & 7;

  const int tid  = threadIdx.x;
  const int wave = tid >> 6;
  const int lane = tid & 63;
  const int g = lane >> 4;
  const int c = lane & 15;

  int buf = 0;

  for (int phase = 0; phase < 2; ++phase) {
    const int qt = phase ? (31 - bx) : bx;
    const int q0 = qt * 64 + wave * 16;

    bf16x8 qf[3];
    {
      const size_t qb = ((size_t)(b * Tn + q0 + c)) * NQKV + h * HSn;
      #pragma unroll
      for (int kk = 0; kk < 3; ++kk)
        qf[kk] = *(const bf16x8*)(qkv + qb + kk * 32 + g * 8);
    }

    f32x4 yacc[6] = {};
    float mrow[4] = {-1e30f, -1e30f, -1e30f, -1e30f};
    float lrow[4] = {};

    // prologue: tile 0 into regs
    bf16x8 kreg[3], vreg[3];
    #pragma unroll
    for (int t = 0; t < 3; ++t) {
      const int i = tid + 256 * t;
      const int kr = i / 12, kc = i % 12;
      kreg[t] = *(const bf16x8*)(
          qkv + ((size_t)(b * Tn + kr)) * NQKV + Cn + h * HSn + kc * 8);
      const int vr = i & 63, vc = i >> 6;
      vreg[t] = *(const bf16x8*)(
          qkv + ((size_t)(b * Tn + vr)) * NQKV + 2 * Cn + h * HSn + vc * 8);
    }

    for (int kt = 0; kt <= qt; ++kt) {
      // ---- reg -> LDS (swizzled). V write is safe: end-barrier below.
      #pragma unroll
      for (int t = 0; t < 3; ++t) {
        const int i = tid + 256 * t;
        const int kr = i / 12, kc = i % 12;
        *(bf16x8*)&KsBuf[(buf * 64 + kr) * 128 + ((kc ^ (kr & 7)) * 8)] = kreg[t];
        const int vr = i & 63, vc = i >> 6;
        #pragma unroll
        for (int u = 0; u < 8; ++u)
          VtBuf[(vc * 8 + u) * 64 + (vr ^ (u * 8))] = vreg[t][u];
      }
      __syncthreads();

      // ---- issue next tile's global loads (land during compute below)
      if (kt < qt) {
        const int k0n = (kt + 1) * 64;
        #pragma unroll
        for (int t = 0; t < 3; ++t) {
          const int i = tid + 256 * t;
          const int kr = i / 12, kc = i % 12;
          kreg[t] = *(const bf16x8*)(
              qkv + ((size_t)(b * Tn + k0n + kr)) * NQKV + Cn + h * HSn + kc * 8);
          const int vr = i & 63, vc = i >> 6;
          vreg[t] = *(const bf16x8*)(
              qkv + ((size_t)(b * Tn + k0n + vr)) * NQKV + 2 * Cn + h * HSn + vc * 8);
        }
      }

      const int k0 = kt * 64;

      // ---- S = Q K^T (scale folded into Q)
      f32x4 s[4] = {};
      __builtin_amdgcn_s_setprio(1);
      #pragma unroll
      for (int kk = 0; kk < 3; ++kk) {
        #pragma unroll
        for (int t = 0; t < 4; ++t) {
          bf16x8 kf = *(const bf16x8*)
              &KsBuf[(buf * 64 + 16 * t + c) * 128 + (((4 * kk + g) ^ (c & 7)) * 8)];
          s[t] = __builtin_amdgcn_mfma_f32_16x16x32_bf16(qf[kk], kf, s[t], 0, 0, 0);
        }
      }
      __builtin_amdgcn_s_setprio(0);
      if (kt == qt) {
        #pragma unroll
        for (int t = 0; t < 4; ++t)
          #pragma unroll
          for (int r = 0; r < 4; ++r)
            if (k0 + 16 * t + c > q0 + 4 * g + r) s[t][r] = -1e30f;
      }

      // ---- online softmax
      #pragma unroll
      for (int r = 0; r < 4; ++r) {
        float mx = fmaxf(fmaxf(s[0][r], s[1][r]), fmaxf(s[2][r], s[3][r]));
        mx = fmaxf(mx, __shfl_xor(mx, 1));
        mx = fmaxf(mx, __shfl_xor(mx, 2));
        mx = fmaxf(mx, __shfl_xor(mx, 4));
        mx = fmaxf(mx, __shfl_xor(mx, 8));
        const float mnew = fmaxf(mrow[r], mx);
        const float corr = __expf(mrow[r] - mnew);
        mrow[r] = mnew;
        lrow[r] *= corr;
        #pragma unroll
        for (int dt = 0; dt < 6; ++dt) yacc[dt][r] *= corr;
        float ls = 0.f;
        const int prow = 4 * g + r;
        #pragma unroll
        for (int t = 0; t < 4; ++t) {
          const float pv = __expf(s[t][r] - mnew);
          ls += pv;
          PlBuf[(wave * 16 + prow) * 64 + ((16 * t + c) ^ ((prow & 7) * 8))] = f2bf(pv);
        }
        lrow[r] += ls;
      }

      // ---- Y += P V
      __builtin_amdgcn_s_setprio(1);
      #pragma unroll
      for (int ks = 0; ks < 2; ++ks) {
        bf16x8 pf = *(const bf16x8*)
            &PlBuf[(wave * 16 + c) * 64 + (((4 * ks + g) ^ (c & 7)) * 8)];
        #pragma unroll
        for (int dt = 0; dt < 6; ++dt) {
          bf16x8 vf = *(const bf16x8*)
              &VtBuf[(16 * dt + c) * 64 + (((4 * ks + g) ^ (c & 7)) * 8)];
          yacc[dt] = __builtin_amdgcn_mfma_f32_16x16x32_bf16(pf, vf, yacc[dt], 0, 0, 0);
        }
      }
      __builtin_amdgcn_s_setprio(0);

      __syncthreads();   // all waves done with VtBuf before next overwrite
      buf ^= 1;
    }

    // ---- epilogue
    #pragma unroll
    for (int r = 0; r < 4; ++r) {
      float v = lrow[r];
      v += __shfl_xor(v, 1);
      v += __shfl_xor(v, 2);
      v += __shfl_xor(v, 4);
      v += __shfl_xor(v, 8);
      lrow[r] = 1.f / (v + 1e-6f);
    }
    #pragma unroll
    for (int dt = 0; dt < 6; ++dt)
      #pragma unroll
      for (int r = 0; r < 4; ++r)
        y[((size_t)(b * Tn + q0 + 4 * g + r)) * Cn + h * HSn + 16 * dt + c] =
            f2bf(yacc[dt][r] * lrow[r]);
  }
}

// ---------------------------------------------------------------------------
extern "C" void kernel_launch(void* const* d_in, const int* in_sizes, int n_in,
                              void* d_out, int out_size, void* d_ws, size_t ws_size,
                              hipStream_t stream) {
  const float* x      = (const float*)d_in[0];
  const float* w_attn = (const float*)d_in[1];
  const float* b_attn = (const float*)d_in[2];
  const float* w_proj = (const float*)d_in[3];
  const float* b_proj = (const float*)d_in[4];
  float* out = (float*)d_out;

  size_t off = 0;
  short* qkv = (short*)((char*)d_ws + off); off += (size_t)MR * NQKV * 2;
  short* xb  = (short*)((char*)d_ws + off); off += (size_t)MR * Cn * 2;
  short* yb  = (short*)((char*)d_ws + off); off += (size_t)MR * Cn * 2;
  short* wat = (short*)((char*)d_ws + off); off += (size_t)Cn * NQKV * 2;
  short* wpt = (short*)((char*)d_ws + off); off += (size_t)Cn * Cn * 2;
  if (ws_size < off) return;

  const float scale = 0.102062072615966f;  // 1/sqrt(96)

  // 0) precision prep
  cvt_bf16<<<(MR * Cn) / (256 * 8), 256, 0, stream>>>(x, xb);
  transpose_bf16<<<dim3(NQKV / 32, Cn / 32), 256, 0, stream>>>(w_attn, wat, Cn, NQKV);
  transpose_bf16<<<dim3(Cn / 32, Cn / 32), 256, 0, stream>>>(w_proj, wpt, Cn, Cn);

  // 1) qkv = x @ w_attn + b_attn   (bf16 out, q columns pre-scaled)
  gemm_mfma<true><<<(NQKV / 128) * (MR / 128), 256, 0, stream>>>(
      xb, wat, b_attn, nullptr, qkv, MR, NQKV, Cn, NQKV / 128, Cn, scale);

  // 2) causal MFMA attention -> y bf16 [B,T,C]
  attn_mfma<<<512, 256, 0, stream>>>(qkv, yb);

  // 3) out = y @ w_proj + b_proj   (fp32 out)
  gemm_mfma<false><<<(Cn / 128) * (MR / 128), 256, 0, stream>>>(
      yb, wpt, b_proj, out, nullptr, MR, Cn, Cn, Cn / 128, 0, 1.f);
}

// Round 7
// 200.537 us; speedup vs baseline: 1.0176x; 1.0176x over previous
//
#include <hip/hip_runtime.h>

// Shapes (fixed): B=4, T=2048, C=768, H=8, hs=96
constexpr int Bn = 4;
constexpr int Tn = 2048;
constexpr int Cn = 768;
constexpr int Hn = 8;
constexpr int HSn = 96;
constexpr int MR = Bn * Tn;       // 8192
constexpr int NQKV = 3 * Cn;      // 2304

typedef __attribute__((ext_vector_type(8))) short bf16x8;
typedef __attribute__((ext_vector_type(4))) float f32x4;

__device__ inline short f2bf(float f) {
  union { float f; unsigned u; } cv; cv.f = f;
  unsigned u = cv.u;
  u += 0x7fffu + ((u >> 16) & 1u);   // RNE; inputs are finite
  return (short)(u >> 16);
}

__device__ inline void gload_lds16(const short* g, short* l) {
  __builtin_amdgcn_global_load_lds(
      (const __attribute__((address_space(1))) unsigned*)g,
      (__attribute__((address_space(3))) unsigned*)l, 16, 0, 0);
}

// ---------------------------------------------------------------------------
// fp32 -> bf16 elementwise (8 elems/thread, exact grid)
// ---------------------------------------------------------------------------
__global__ __launch_bounds__(256) void cvt_bf16(const float* __restrict__ in,
                                                short* __restrict__ out) {
  const size_t i = ((size_t)blockIdx.x * 256 + threadIdx.x) * 8;
  float4 a = *(const float4*)(in + i);
  float4 b = *(const float4*)(in + i + 4);
  bf16x8 o;
  o[0] = f2bf(a.x); o[1] = f2bf(a.y); o[2] = f2bf(a.z); o[3] = f2bf(a.w);
  o[4] = f2bf(b.x); o[5] = f2bf(b.y); o[6] = f2bf(b.z); o[7] = f2bf(b.w);
  *(bf16x8*)(out + i) = o;
}

// ---------------------------------------------------------------------------
// W [K][N] fp32 -> Wt [N][K] bf16 (32x32 LDS tile transpose)
// ---------------------------------------------------------------------------
__global__ __launch_bounds__(256) void transpose_bf16(
    const float* __restrict__ W, short* __restrict__ Wt, int K, int N) {
  __shared__ float t[32][33];
  const int n0 = blockIdx.x * 32, k0 = blockIdx.y * 32;
  const int tx = threadIdx.x & 31, ty = threadIdx.x >> 5;
  #pragma unroll
  for (int i = 0; i < 32; i += 8)
    t[ty + i][tx] = W[(size_t)(k0 + ty + i) * N + n0 + tx];
  __syncthreads();
  #pragma unroll
  for (int i = 0; i < 32; i += 8)
    Wt[(size_t)(n0 + ty + i) * K + k0 + tx] = f2bf(t[tx][ty + i]);
}

// ---------------------------------------------------------------------------
// Vt builder: per (b,h,kvtile) transpose V [64 keys][96 dims] -> [96][64].
// vt layout: [((b*8+h)*32 + kt)][dim 0..95][key 0..63], 6144 shorts/tile.
// Grid = B*H*32 = 1024 blocks, 256 threads.
// ---------------------------------------------------------------------------
__global__ __launch_bounds__(256) void build_vt(
    const short* __restrict__ qkv, short* __restrict__ vt) {
  __shared__ short Vl[64][104];   // rows padded to 208 B
  const int blk = blockIdx.x;
  const int kt = blk & 31, bh = blk >> 5;
  const int b = bh >> 3, h = bh & 7;
  const int k0 = kt * 64;
  const int tid = threadIdx.x;

  #pragma unroll
  for (int i = tid; i < 768; i += 256) {
    const int r = i / 12, ch = i % 12;
    *(bf16x8*)&Vl[r][ch * 8] = *(const bf16x8*)(
        qkv + ((size_t)(b * Tn + k0 + r)) * NQKV + 2 * Cn + h * HSn + ch * 8);
  }
  __syncthreads();
  #pragma unroll
  for (int i = tid; i < 768; i += 256) {
    const int d = i >> 3, w = i & 7;
    bf16x8 o;
    #pragma unroll
    for (int u = 0; u < 8; ++u) o[u] = Vl[w * 8 + u][d];
    *(bf16x8*)(vt + (size_t)blk * 6144 + d * 64 + w * 8) = o;
  }
}

// ---------------------------------------------------------------------------
// bf16 MFMA GEMM (m97 structure): C[M,N] = A[M,K] @ Bt[N,K]^T + bias[N]
// 1D grid with bijective XCD-chunked remap (gridDim.x % 8 == 0).
// ---------------------------------------------------------------------------
template <bool BF16OUT>
__global__ __launch_bounds__(256) void gemm_mfma(
    const short* __restrict__ A, const short* __restrict__ Bt,
    const float* __restrict__ bias, float* __restrict__ Cf,
    short* __restrict__ Cb, int M, int N, int K, int nxTiles,
    int scale_cols, float scale) {
  __shared__ short As[128 * 32];
  __shared__ short Bs[128 * 32];

  const int cpx = gridDim.x >> 3;
  const int lin = blockIdx.x;
  const int remap = (lin & 7) * cpx + (lin >> 3);   // XCD-chunked, bijective
  const int bxt = remap % nxTiles, byt = remap / nxTiles;

  const int tid  = threadIdx.x;
  const int wave = tid >> 6, lane = tid & 63;
  const int bm = byt * 128, bn = bxt * 128;
  const int wr = wave >> 1, wc = wave & 1;
  const int g = lane >> 4, c = lane & 15;

  f32x4 acc[4][4] = {};

  for (int k0 = 0; k0 < K; k0 += 32) {
    __syncthreads();
    #pragma unroll
    for (int cc = 0; cc < 2; ++cc) {
      const int chunkbase = (wave * 2 + cc) * 64;
      const int chunk = chunkbase + lane;
      const int row = chunk >> 2, col16 = chunk & 3;
      gload_lds16(A + (size_t)(bm + row) * K + k0 + col16 * 8,
                  &As[chunkbase * 8]);
      gload_lds16(Bt + (size_t)(bn + row) * K + k0 + col16 * 8,
                  &Bs[chunkbase * 8]);
    }
    __syncthreads();

    bf16x8 af[4], bfr[4];
    #pragma unroll
    for (int m = 0; m < 4; ++m)
      af[m] = *(const bf16x8*)&As[(wr * 64 + m * 16 + c) * 32 + g * 8];
    #pragma unroll
    for (int n = 0; n < 4; ++n)
      bfr[n] = *(const bf16x8*)&Bs[(wc * 64 + n * 16 + c) * 32 + g * 8];
    #pragma unroll
    for (int m = 0; m < 4; ++m)
      #pragma unroll
      for (int n = 0; n < 4; ++n)
        acc[m][n] = __builtin_amdgcn_mfma_f32_16x16x32_bf16(af[m], bfr[n], acc[m][n], 0, 0, 0);
  }

  #pragma unroll
  for (int n = 0; n < 4; ++n) {
    const int col = bn + wc * 64 + n * 16 + c;
    const float bs = bias[col];
    const float sc = (BF16OUT && col < scale_cols) ? scale : 1.f;
    #pragma unroll
    for (int m = 0; m < 4; ++m) {
      #pragma unroll
      for (int r = 0; r < 4; ++r) {
        const int row = bm + wr * 64 + m * 16 + g * 4 + r;
        const float v = acc[m][n][r] + bs;
        if (BF16OUT) Cb[(size_t)row * N + col] = f2bf(v * sc);
        else         Cf[(size_t)row * N + col] = v;
      }
    }
  }
}

// ---------------------------------------------------------------------------
// Causal flash attention, bf16 MFMA, fp32 accumulate.
// 4 waves/block, 16 q-rows/wave, q-tile pair {bx, 31-bx}, XCD remap.
// K: global_load_lds (width 16) into double-buffered subtiled LDS
//    [kb=key/4][db=dim/16][key&3][dim&15] (verified mapping), 1 barrier/tile.
// V: direct global b128 fragment loads from pre-transposed vt (no LDS).
// Softmax in exp2 domain (scale*log2e folded into q).
// LDS = 33,792 B.
// ---------------------------------------------------------------------------
__global__ __launch_bounds__(256) void attn_mfma(
    const short* __restrict__ qkv, const short* __restrict__ vt,
    short* __restrict__ y) {
  __shared__ short Ksub[2][6144];   // 24,576 B
  __shared__ short Pl[4][16][72];   //  9,216 B

  const int bid = blockIdx.x;
  const int xcd = bid & 7, jj = bid >> 3;
  const int p = xcd + 8 * (jj >> 4);     // (b,h) pair 0..31
  const int bx = jj & 15;
  const int b = p >> 3, h = p & 7;

  const int tid  = threadIdx.x;
  const int wave = tid >> 6;
  const int lane = tid & 63;
  const int g = lane >> 4;
  const int c = lane & 15;

  // loop-invariant fragment address pieces
  const int klane = ((c >> 2) * 6 + (g >> 1)) * 64 + (c & 3) * 16 + (g & 1) * 8;
  const int voff  = c * 64 + g * 8;                       // within a vt tile
  const short* vtb = vt + (size_t)((b * 8 + h) * 32) * 6144;

  for (int phase = 0; phase < 2; ++phase) {
    const int qt = phase ? (31 - bx) : bx;
    const int q0 = qt * 64 + wave * 16;

    bf16x8 qf[3];
    {
      const size_t qb = ((size_t)(b * Tn + q0 + c)) * NQKV + h * HSn;
      #pragma unroll
      for (int kk = 0; kk < 3; ++kk)
        qf[kk] = *(const bf16x8*)(qkv + qb + kk * 32 + g * 8);
    }

    // K staging source pointers (per-lane, pre-permuted for subtiled dest)
    const short* kap[3];
    #pragma unroll
    for (int j = 0; j < 3; ++j) {
      const int ci = (j * 4 + wave) * 64 + lane;
      const int s = ci >> 3;
      const int kb = s / 6, db = s - kb * 6;
      const int r = kb * 4 + ((ci & 7) >> 1);
      const int d0 = db * 16 + (ci & 1) * 8;
      kap[j] = qkv + ((size_t)(b * Tn + r)) * NQKV + Cn + h * HSn + d0;
    }
    // prologue: async-stage K tile 0 into Ksub[0]
    #pragma unroll
    for (int j = 0; j < 3; ++j) {
      gload_lds16(kap[j], &Ksub[0][(j * 4 + wave) * 512]);
      kap[j] += 64 * NQKV;
    }

    f32x4 yacc[6] = {};
    float mrow[4] = {-1e30f, -1e30f, -1e30f, -1e30f};
    float lrow[4] = {};
    int buf = 0;

    for (int kt = 0; kt <= qt; ++kt) {
      __syncthreads();   // drains vmcnt -> K tile kt resident in Ksub[buf]

      // issue next K tile into Ksub[buf^1] (lands during compute)
      if (kt < qt) {
        #pragma unroll
        for (int j = 0; j < 3; ++j) {
          gload_lds16(kap[j], &Ksub[buf ^ 1][(j * 4 + wave) * 512]);
          kap[j] += 64 * NQKV;
        }
      }

      // V fragments for THIS tile: plain global b128 loads (L2-hot via remap);
      // issued here so latency hides under QK^T + softmax.
      const short* vtile = vtb + (size_t)kt * 6144 + voff;
      bf16x8 vf[12];
      #pragma unroll
      for (int ks = 0; ks < 2; ++ks)
        #pragma unroll
        for (int dt = 0; dt < 6; ++dt)
          vf[ks * 6 + dt] = *(const bf16x8*)(vtile + dt * 1024 + ks * 32);

      const int k0 = kt * 64;

      // ---- S = Q K^T  (scale * log2e folded into Q)
      f32x4 s[4] = {};
      __builtin_amdgcn_s_setprio(1);
      #pragma unroll
      for (int kk = 0; kk < 3; ++kk) {
        #pragma unroll
        for (int t = 0; t < 4; ++t) {
          bf16x8 kf = *(const bf16x8*)&Ksub[buf][klane + (24 * t + 2 * kk) * 64];
          s[t] = __builtin_amdgcn_mfma_f32_16x16x32_bf16(qf[kk], kf, s[t], 0, 0, 0);
        }
      }
      __builtin_amdgcn_s_setprio(0);
      if (kt == qt) {
        #pragma unroll
        for (int t = 0; t < 4; ++t)
          #pragma unroll
          for (int r = 0; r < 4; ++r)
            if (k0 + 16 * t + c > q0 + 4 * g + r) s[t][r] = -1e30f;
      }

      // ---- online softmax (exp2 domain)
      #pragma unroll
      for (int r = 0; r < 4; ++r) {
        float mx = fmaxf(fmaxf(s[0][r], s[1][r]), fmaxf(s[2][r], s[3][r]));
        mx = fmaxf(mx, __shfl_xor(mx, 1));
        mx = fmaxf(mx, __shfl_xor(mx, 2));
        mx = fmaxf(mx, __shfl_xor(mx, 4));
        mx = fmaxf(mx, __shfl_xor(mx, 8));
        const float mnew = fmaxf(mrow[r], mx);
        const float corr = exp2f(mrow[r] - mnew);
        mrow[r] = mnew;
        lrow[r] *= corr;
        #pragma unroll
        for (int dt = 0; dt < 6; ++dt) yacc[dt][r] *= corr;
        float ls = 0.f;
        #pragma unroll
        for (int t = 0; t < 4; ++t) {
          const float pv = exp2f(s[t][r] - mnew);
          ls += pv;
          Pl[wave][4 * g + r][16 * t + c] = f2bf(pv);
        }
        lrow[r] += ls;
      }

      // ---- Y += P V  (P via same-wave LDS round-trip; V from registers)
      __builtin_amdgcn_s_setprio(1);
      #pragma unroll
      for (int ks = 0; ks < 2; ++ks) {
        bf16x8 pf = *(const bf16x8*)&Pl[wave][c][ks * 32 + g * 8];
        #pragma unroll
        for (int dt = 0; dt < 6; ++dt)
          yacc[dt] = __builtin_amdgcn_mfma_f32_16x16x32_bf16(pf, vf[ks * 6 + dt], yacc[dt], 0, 0, 0);
      }
      __builtin_amdgcn_s_setprio(0);

      buf ^= 1;
    }

    // ---- epilogue
    #pragma unroll
    for (int r = 0; r < 4; ++r) {
      float v = lrow[r];
      v += __shfl_xor(v, 1);
      v += __shfl_xor(v, 2);
      v += __shfl_xor(v, 4);
      v += __shfl_xor(v, 8);
      lrow[r] = 1.f / (v + 1e-6f);
    }
    #pragma unroll
    for (int dt = 0; dt < 6; ++dt)
      #pragma unroll
      for (int r = 0; r < 4; ++r)
        y[((size_t)(b * Tn + q0 + 4 * g + r)) * Cn + h * HSn + 16 * dt + c] =
            f2bf(yacc[dt][r] * lrow[r]);
  }
}

// ---------------------------------------------------------------------------
extern "C" void kernel_launch(void* const* d_in, const int* in_sizes, int n_in,
                              void* d_out, int out_size, void* d_ws, size_t ws_size,
                              hipStream_t stream) {
  const float* x      = (const float*)d_in[0];
  const float* w_attn = (const float*)d_in[1];
  const float* b_attn = (const float*)d_in[2];
  const float* w_proj = (const float*)d_in[3];
  const float* b_proj = (const float*)d_in[4];
  float* out = (float*)d_out;

  size_t off = 0;
  short* qkv = (short*)((char*)d_ws + off); off += (size_t)MR * NQKV * 2;
  short* xb  = (short*)((char*)d_ws + off); off += (size_t)MR * Cn * 2;   // also vt
  short* yb  = (short*)((char*)d_ws + off); off += (size_t)MR * Cn * 2;
  short* wat = (short*)((char*)d_ws + off); off += (size_t)Cn * NQKV * 2;
  short* wpt = (short*)((char*)d_ws + off); off += (size_t)Cn * Cn * 2;
  if (ws_size < off) return;
  short* vt = xb;   // xb is dead after GEMM1; vt is exactly MR*Cn shorts

  // 1/sqrt(96) * log2(e): softmax runs in exp2 domain
  const float scale = 0.102062072615966f * 1.4426950408889634f;

  // 0) precision prep
  cvt_bf16<<<(MR * Cn) / (256 * 8), 256, 0, stream>>>(x, xb);
  transpose_bf16<<<dim3(NQKV / 32, Cn / 32), 256, 0, stream>>>(w_attn, wat, Cn, NQKV);
  transpose_bf16<<<dim3(Cn / 32, Cn / 32), 256, 0, stream>>>(w_proj, wpt, Cn, Cn);

  // 1) qkv = x @ w_attn + b_attn   (bf16 out, q columns pre-scaled)
  gemm_mfma<true><<<(NQKV / 128) * (MR / 128), 256, 0, stream>>>(
      xb, wat, b_attn, nullptr, qkv, MR, NQKV, Cn, NQKV / 128, Cn, scale);

  // 1b) materialize V^T tiles (reuses xb storage — xb consumed by GEMM1)
  build_vt<<<Bn * Hn * 32, 256, 0, stream>>>(qkv, vt);

  // 2) causal MFMA attention -> y bf16 [B,T,C]
  attn_mfma<<<512, 256, 0, stream>>>(qkv, vt, yb);

  // 3) out = y @ w_proj + b_proj   (fp32 out)
  gemm_mfma<false><<<(Cn / 128) * (MR / 128), 256, 0, stream>>>(
      yb, wpt, b_proj, out, nullptr, MR, Cn, Cn, Cn / 128, 0, 1.f);
}